// Round 8
// baseline (486.001 us; speedup 1.0000x reference)
//
#include <hip/hip_runtime.h>

// ELKUNet forward on MI355X — round 8. f32 device tensors (proven r1/r2/r4/r5).
// r7 lesson (VGPR_Count=72): one kernel holding W[64]+W13[64] exceeds the
// default launch-bounds VGPR budget -> compiler sinks W13 into the loop and
// re-loads 16KB/point. Fix: split into k_pre1 (W_pre+LN) and k_pre2 (W13),
// each with exactly one resident 64-float weight array.
// k_final: prefetch first neighbor's feats row in the B-stage (4 uniform
// float4s = all 4 cachelines) — the last unprefetched critical-path load.

typedef unsigned int u32;
typedef unsigned long long u64;

#define EPSV 1e-6f
#define HBITS 20
#define HSIZE (1u << HBITS)
#define HMASK (HSIZE - 1u)

template<int C,int R> __device__ __forceinline__ float dpp_add(float x){
    int y = __builtin_amdgcn_update_dpp(0, __float_as_int(x), C, R, 0xf, true);
    return x + __int_as_float(y);
}
// full 64-lane sum broadcast to all lanes; pure VALU + 1 readlane.
__device__ __forceinline__ float wave_sum(float x){
    x = dpp_add<0xB1,0xF>(x);   // xor 1
    x = dpp_add<0x4E,0xF>(x);   // xor 2
    x = dpp_add<0x141,0xF>(x);  // xor 4
    x = dpp_add<0x140,0xF>(x);  // xor 8
    x = dpp_add<0x142,0xA>(x);  // row_bcast:15
    x = dpp_add<0x143,0xC>(x);  // row_bcast:31
    return __int_as_float(__builtin_amdgcn_readlane(__float_as_int(x), 63));
}

__device__ __forceinline__ u32 hslot(u32 b){ return (b * 0x9E3779B1u) >> (32 - HBITS); }

__global__ void k_scatter(const int* __restrict__ coords, u64* __restrict__ hash,
                          u32* __restrict__ bm, int n){
    int i = blockIdx.x * blockDim.x + threadIdx.x;
    if(i < n){
        int4 c = ((const int4*)coords)[i];
        u32 b = ((u32)c.x << 16) | ((u32)c.y << 8) | (u32)c.z;
        atomicOr(&bm[b >> 5], 1u << (b & 31));
        u64 entry = ((u64)b << 32) | (u32)i;
        u32 s = hslot(b);
        while(atomicCAS(&hash[s], ~0ull, entry) != ~0ull) s = (s + 1) & HMASK;
    }
}

// 1 thread per (point, direction): bitmap probe -> hash lookup -> append list.
__global__ void k_nbr(const int* __restrict__ coords, const u64* __restrict__ hash,
                      const u32* __restrict__ bm, u32* __restrict__ nbrcnt,
                      u32* __restrict__ nbrlst, int n){
    int t = blockIdx.x * blockDim.x + threadIdx.x;
    int pt = t / 27;
    if(pt >= n) return;
    int d = t - pt * 27;
    if(d == 13) return;                          // self handled densely in k_pre2
    int4 c = ((const int4*)coords)[pt];
    int nx = c.x + d / 9 - 1, ny = c.y + (d / 3) % 3 - 1, nz = c.z + d % 3 - 1;
    if(((u32)nx >= 256u) | ((u32)ny >= 256u) | ((u32)nz >= 256u)) return;
    u32 b = ((u32)nx << 16) | ((u32)ny << 8) | (u32)nz;
    if(!((bm[b >> 5] >> (b & 31)) & 1u)) return;
    u32 s = hslot(b);
    u64 e;
    while((u32)((e = hash[s]) >> 32) != b) s = (s + 1) & HMASK;
    u32 slot = atomicAdd(&nbrcnt[pt], 1u);
    if(slot < 8u) nbrlst[(size_t)pt * 8 + slot] = ((u32)d << 25) | (u32)e;
}

// F_input = LN(feats @ W_pre^T). ONE resident weight array.
__launch_bounds__(256)
__global__ void k_pre1(const float* __restrict__ feats, const float* __restrict__ W_pre,
                       const float* __restrict__ lnw, const float* __restrict__ lnb,
                       float* __restrict__ F_input, int n, int nwaves){
    const int lane = threadIdx.x & 63;
    const int wave = (blockIdx.x * blockDim.x + threadIdx.x) >> 6;

    float W[64];   // W_pre[lane][j]
    {   const float4* wr = (const float4*)(W_pre + (size_t)lane * 64);
#pragma unroll
        for(int q = 0; q < 16; ++q){
            float4 v = wr[q];
            W[4*q] = v.x; W[4*q+1] = v.y; W[4*q+2] = v.z; W[4*q+3] = v.w;
        }
    }
    const float lw = lnw[lane], lb = lnb[lane];

    for(int i = wave; i < n; i += nwaves){
        const int si = __builtin_amdgcn_readfirstlane(i);
        const float4* fr = (const float4*)(feats + (size_t)si * 64);
        float a0=0.f, a1=0.f, a2=0.f, a3=0.f;
#pragma unroll
        for(int q = 0; q < 16; ++q){
            float4 f = fr[q];
            a0 = fmaf(f.x, W[4*q],   a0);
            a1 = fmaf(f.y, W[4*q+1], a1);
            a2 = fmaf(f.z, W[4*q+2], a2);
            a3 = fmaf(f.w, W[4*q+3], a3);
        }
        float acc = (a0 + a1) + (a2 + a3);
        float m = wave_sum(acc) * (1.f/64.f);
        float t = acc - m;
        float v = wave_sum(t*t) * (1.f/64.f);
        F_input[(size_t)si*64 + lane] = t * rsqrtf(v + EPSV) * lw + lb;
    }
}

// selfconv = feats @ conv_w[13]. ONE resident weight array.
__launch_bounds__(256)
__global__ void k_pre2(const float* __restrict__ feats, const float* __restrict__ conv_w,
                       float* __restrict__ selfconv, int n, int nwaves){
    const int lane = threadIdx.x & 63;
    const int wave = (blockIdx.x * blockDim.x + threadIdx.x) >> 6;

    float W13[64]; // conv_w[13][j][lane]
#pragma unroll
    for(int j = 0; j < 64; ++j) W13[j] = conv_w[(13*64 + j)*64 + lane];

    for(int i = wave; i < n; i += nwaves){
        const int si = __builtin_amdgcn_readfirstlane(i);
        const float4* fr = (const float4*)(feats + (size_t)si * 64);
        float s0=0.f, s1=0.f, s2=0.f, s3=0.f;
#pragma unroll
        for(int q = 0; q < 16; ++q){
            float4 f = fr[q];
            s0 = fmaf(f.x, W13[4*q],   s0);
            s1 = fmaf(f.y, W13[4*q+1], s1);
            s2 = fmaf(f.z, W13[4*q+2], s2);
            s3 = fmaf(f.w, W13[4*q+3], s3);
        }
        selfconv[(size_t)si*64 + lane] = (s0 + s1) + (s2 + s3);
    }
}

// Segment sums: 1 wave = 1 segment; lane-parallel hash probes; no atomics.
__launch_bounds__(256)
__global__ void k_seg(const float* __restrict__ F_input, const u64* __restrict__ hash,
                      const u64* __restrict__ bm64, const float* __restrict__ W_pos,
                      const float* __restrict__ alpha,
                      float* __restrict__ sums, float* __restrict__ counts){
    const int lane = threadIdx.x & 63;
    const int seg  = (blockIdx.x << 2) + (threadIdx.x >> 6);
    const int cx = seg >> 10, cy = (seg >> 5) & 31, cz = seg & 31;

    const int px = (cx << 3) + (lane >> 3), py = (cy << 3) + (lane & 7);
    u64 w = bm64[((size_t)px << 10) | ((u32)py << 2) | (u32)(cz >> 3)];
    u32 o8 = (u32)(w >> ((cz & 7) * 8)) & 0xffu;
    float cnt = wave_sum((float)__popc(o8));

    const float wx = W_pos[lane*3+0], wy = W_pos[lane*3+1], wz = W_pos[lane*3+2];
    const float al = alpha[lane];

    float aC = 0.f, aS = 0.f, aL = 0.f;
    while(__ballot(o8 != 0u)){
        int myz = 0, pid = -1;
        if(o8){
            int dz = __ffs(o8) - 1; o8 &= o8 - 1;
            myz = (cz << 3) + dz;
            u32 b = ((u32)px << 16) | ((u32)py << 8) | (u32)myz;
            u32 s = hslot(b); u64 e;
            while((u32)((e = hash[s]) >> 32) != b) s = (s + 1) & HMASK;   // lane-parallel
            pid = (int)(u32)e;
        }
        u64 mm = __ballot(pid >= 0);
        while(mm){
            int l = __ffsll(mm) - 1; mm &= mm - 1;
            int p  = __builtin_amdgcn_readlane(pid, l);
            int pz = __builtin_amdgcn_readlane(myz, l);
            int qx = (cx << 3) + (l >> 3), qy = (cy << 3) + (l & 7);
            float F = F_input[(size_t)p * 64 + lane];
            float pos = ((float)qx*wx + (float)qy*wy + (float)pz*wz) * al;
            aC = fmaf(F, __cosf(pos), aC);
            aS = fmaf(F, __sinf(pos), aS);
            aL = fmaf(F, pos, aL);
        }
    }
    float* sp = sums + (size_t)seg * 192;
    sp[lane] = aC; sp[64 + lane] = aS; sp[128 + lane] = aL;
    if(lane == 0) counts[seg] = cnt;
}

// Software-pipelined final; first-neighbor feats row prefetched in B-stage.
__launch_bounds__(256)
__global__ void k_final(const float* __restrict__ feats,
                        const float* __restrict__ F_input,
                        const float* __restrict__ selfconv,
                        const float* __restrict__ W_pos, const float* __restrict__ alpha,
                        const float* __restrict__ conv_w,
                        const float* __restrict__ ln_w, const float* __restrict__ ln_b,
                        const float* __restrict__ lnl_w, const float* __restrict__ lnl_b,
                        const int* __restrict__ coords,
                        const float* __restrict__ sums, const float* __restrict__ counts,
                        const u32* __restrict__ nbrcnt, const u32* __restrict__ nbrlst,
                        float* __restrict__ out, int n, int nwaves){
    const int lane = threadIdx.x & 63;
    const int wave = (blockIdx.x * blockDim.x + threadIdx.x) >> 6;

    const float wx = W_pos[lane*3+0], wy = W_pos[lane*3+1], wz = W_pos[lane*3+2];
    const float al = alpha[lane];
    const float lnwv = ln_w[lane], lnbv = ln_b[lane];
    const float llwv = lnl_w[lane], llbv = lnl_b[lane];

    int i = wave;
    if(i >= n) return;

    int siA = __builtin_amdgcn_readfirstlane(i);
    int4 cA = ((const int4*)coords)[siA];
    int segA = ((cA.x >> 3) << 10) | ((cA.y >> 3) << 5) | (cA.z >> 3);
    const float* spA = sums + (size_t)segA * 192;
    float s0A = spA[lane], s1A = spA[64+lane], s2A = spA[128+lane];
    float cntA = counts[segA];
    float FA = F_input[(size_t)siA*64 + lane];
    float ScA = selfconv[(size_t)siA*64 + lane];
    u32 ncA = nbrcnt[siA];
    u32 e0A = nbrlst[(size_t)siA*8];
    float4 pfA0, pfA1, pfA2, pfA3;
    {   u32 pi0 = ncA ? (e0A & 0x1FFFFFFu) : 0u;
        const float4* gv = (const float4*)(feats + (size_t)pi0 * 64);
        pfA0 = gv[0]; pfA1 = gv[4]; pfA2 = gv[8]; pfA3 = gv[12];
    }

    for(; i < n; ){
        const int inext = i + nwaves;
        const bool hB = inext < n;
        int siB = 0; int4 cB = cA; float s0B=0,s1B=0,s2B=0,cntB=0,FB=0,ScB=0;
        u32 ncB = 0, e0B = 0;
        float4 pfB0=pfA0, pfB1=pfA1, pfB2=pfA2, pfB3=pfA3;
        if(hB){
            siB = __builtin_amdgcn_readfirstlane(inext);
            cB = ((const int4*)coords)[siB];
            int segB = ((cB.x >> 3) << 10) | ((cB.y >> 3) << 5) | (cB.z >> 3);
            const float* spB = sums + (size_t)segB * 192;
            s0B = spB[lane]; s1B = spB[64+lane]; s2B = spB[128+lane];
            cntB = counts[segB];
            FB = F_input[(size_t)siB*64 + lane];
            ScB = selfconv[(size_t)siB*64 + lane];
            ncB = nbrcnt[siB];
            e0B = nbrlst[(size_t)siB*8];
            u32 pi0 = ncB ? (e0B & 0x1FFFFFFu) : 0u;
            const float4* gv = (const float4*)(feats + (size_t)pi0 * 64);
            pfB0 = gv[0]; pfB1 = gv[4]; pfB2 = gv[8]; pfB3 = gv[12];
        }

        // ---- compute A ----
        float pos = ((float)cA.x*wx + (float)cA.y*wy + (float)cA.z*wz) * al;
        float sn = __sinf(pos), cs = __cosf(pos);
        float inv = 1.f / fmaxf(cntA, 1.f);
        float newF = fmaf(s0A*inv, cs, fmaf(s1A*inv, sn, s2A*inv - FA*pos));
        float local = ScA;

        u32 cc = ncA > 8u ? 8u : ncA;
        if(cc){
            // first neighbor: q=0,4,8,12 from prefetch (all 4 cachelines warm)
            {   u32 k = e0A >> 25, pi = e0A & 0x1FFFFFFu;
                const float4* gv = (const float4*)(feats + (size_t)pi * 64);
                const float* cw = conv_w + (size_t)k * 4096;
#pragma unroll
                for(int q = 0; q < 16; ++q){
                    float4 g = (q==0)?pfA0 : (q==4)?pfA1 : (q==8)?pfA2 : (q==12)?pfA3 : gv[q];
                    local = fmaf(g.x, cw[(4*q    )*64 + lane], local);
                    local = fmaf(g.y, cw[(4*q + 1)*64 + lane], local);
                    local = fmaf(g.z, cw[(4*q + 2)*64 + lane], local);
                    local = fmaf(g.w, cw[(4*q + 3)*64 + lane], local);
                }
            }
            for(u32 c2 = 1; c2 < cc; ++c2){
                u32 e = nbrlst[(size_t)siA*8 + c2];
                u32 k = e >> 25, pi = e & 0x1FFFFFFu;
                const float4* gv = (const float4*)(feats + (size_t)pi * 64);
                const float* cw = conv_w + (size_t)k * 4096;
#pragma unroll
                for(int q = 0; q < 16; ++q){
                    float4 g = gv[q];
                    local = fmaf(g.x, cw[(4*q    )*64 + lane], local);
                    local = fmaf(g.y, cw[(4*q + 1)*64 + lane], local);
                    local = fmaf(g.z, cw[(4*q + 2)*64 + lane], local);
                    local = fmaf(g.w, cw[(4*q + 3)*64 + lane], local);
                }
            }
        }

        float m1 = wave_sum(newF) * (1.f/64.f);
        float t1 = newF - m1;
        float v1 = wave_sum(t1*t1) * (1.f/64.f);
        float a1 = t1 * rsqrtf(v1 + EPSV) * lnwv + lnbv;

        float m2 = wave_sum(local) * (1.f/64.f);
        float t2 = local - m2;
        float v2 = wave_sum(t2*t2) * (1.f/64.f);
        float a2 = t2 * rsqrtf(v2 + EPSV) * llwv + llbv;

        out[(size_t)siA*64 + lane] = fmaxf(a1 + a2, 0.f);

        i = inext;
        if(hB){
            siA = siB; cA = cB;
            s0A = s0B; s1A = s1B; s2A = s2B; cntA = cntB;
            FA = FB; ScA = ScB; ncA = ncB; e0A = e0B;
            pfA0 = pfB0; pfA1 = pfB1; pfA2 = pfB2; pfA3 = pfB3;
        }
    }
}

extern "C" void kernel_launch(void* const* d_in, const int* in_sizes, int n_in,
                              void* d_out, int out_size, void* d_ws, size_t ws_size,
                              hipStream_t stream) {
    (void)n_in; (void)out_size; (void)ws_size;
    const float* feats    = (const float*)d_in[0];
    const float* W_pre    = (const float*)d_in[1];
    const float* ln_pre_w = (const float*)d_in[2];
    const float* ln_pre_b = (const float*)d_in[3];
    const float* W_pos    = (const float*)d_in[4];
    const float* alpha    = (const float*)d_in[5];
    const float* conv_w   = (const float*)d_in[6];
    const float* ln_w     = (const float*)d_in[7];
    const float* ln_b     = (const float*)d_in[8];
    const float* lnl_w    = (const float*)d_in[9];
    const float* lnl_b    = (const float*)d_in[10];
    const int*   coords   = (const int*)d_in[11];

    const int n = in_sizes[0] / 64;

    char* ws = (char*)d_ws;
    size_t o = 0;
    u64*   hash    = (u64*)(ws + o);   o += (size_t)HSIZE * 8;          // 8,388,608
    size_t zoff    = o;
    u32*   bm      = (u32*)(ws + o);   o += 2097152;                    // 2MB bitmap
    u64*   bm64    = (u64*)bm;
    u32*   nbrcnt  = (u32*)(ws + o);   o += ((size_t)n*4 + 255) & ~(size_t)255;
    size_t zspan   = o - zoff;
    float* sums    = (float*)(ws + o); o += 25165824;                   // written by k_seg (no memset)
    float* counts  = (float*)(ws + o); o += 131072;                     // written by k_seg
    u32*   nbrlst  = (u32*)(ws + o);   o += (size_t)n * 32;             // 8 slots/pt
    float* F_input = (float*)(ws + o); o += (size_t)n * 256;
    float* selfconv= (float*)(ws + o); o += (size_t)n * 256;

    hipMemsetAsync(hash, 0xFF, (size_t)HSIZE * 8, stream);
    hipMemsetAsync(ws + zoff, 0, zspan, stream);

    k_scatter<<<(n + 255)/256, 256, 0, stream>>>(coords, hash, bm, n);
    k_nbr<<<(n*27 + 255)/256, 256, 0, stream>>>(coords, hash, bm, nbrcnt, nbrlst, n);
    k_pre1<<<2048, 256, 0, stream>>>(feats, W_pre, ln_pre_w, ln_pre_b, F_input, n, 8192);
    k_pre2<<<2048, 256, 0, stream>>>(feats, conv_w, selfconv, n, 8192);
    k_seg<<<8192, 256, 0, stream>>>(F_input, hash, bm64, W_pos, alpha, sums, counts);
    k_final<<<2048, 256, 0, stream>>>(feats, F_input, selfconv, W_pos, alpha, conv_w,
                                      ln_w, ln_b, lnl_w, lnl_b, coords,
                                      sums, counts, nbrcnt, nbrlst,
                                      (float*)d_out, n, 8192);
}

// Round 9
// 342.911 us; speedup vs baseline: 1.4173x; 1.4173x over previous
//
#include <hip/hip_runtime.h>

// ELKUNet forward on MI355X — round 9. f32 device tensors (proven r1/r2/r4/r5).
// r8 lesson: adding 2-stage feats-row prefetch to k_final (+32 live VGPRs at
// VGPR_Count=68) spilled the pipeline state to scratch (WRITE_SIZE 226MB vs
// 51MB of real output) -> 3x slowdown. Reverted k_final to r7's spill-free
// form. Kept the r8 k_pre1/k_pre2 split (one resident 64-float weight array
// per kernel; r7's fused version sank W13 into the loop at VGPR=72).

typedef unsigned int u32;
typedef unsigned long long u64;

#define EPSV 1e-6f
#define HBITS 20
#define HSIZE (1u << HBITS)
#define HMASK (HSIZE - 1u)

template<int C,int R> __device__ __forceinline__ float dpp_add(float x){
    int y = __builtin_amdgcn_update_dpp(0, __float_as_int(x), C, R, 0xf, true);
    return x + __int_as_float(y);
}
// full 64-lane sum broadcast to all lanes; pure VALU + 1 readlane.
__device__ __forceinline__ float wave_sum(float x){
    x = dpp_add<0xB1,0xF>(x);   // xor 1
    x = dpp_add<0x4E,0xF>(x);   // xor 2
    x = dpp_add<0x141,0xF>(x);  // xor 4
    x = dpp_add<0x140,0xF>(x);  // xor 8
    x = dpp_add<0x142,0xA>(x);  // row_bcast:15
    x = dpp_add<0x143,0xC>(x);  // row_bcast:31
    return __int_as_float(__builtin_amdgcn_readlane(__float_as_int(x), 63));
}

__device__ __forceinline__ u32 hslot(u32 b){ return (b * 0x9E3779B1u) >> (32 - HBITS); }

__global__ void k_scatter(const int* __restrict__ coords, u64* __restrict__ hash,
                          u32* __restrict__ bm, int n){
    int i = blockIdx.x * blockDim.x + threadIdx.x;
    if(i < n){
        int4 c = ((const int4*)coords)[i];
        u32 b = ((u32)c.x << 16) | ((u32)c.y << 8) | (u32)c.z;
        atomicOr(&bm[b >> 5], 1u << (b & 31));
        u64 entry = ((u64)b << 32) | (u32)i;
        u32 s = hslot(b);
        while(atomicCAS(&hash[s], ~0ull, entry) != ~0ull) s = (s + 1) & HMASK;
    }
}

// 1 thread per (point, direction): bitmap probe -> hash lookup -> append list.
__global__ void k_nbr(const int* __restrict__ coords, const u64* __restrict__ hash,
                      const u32* __restrict__ bm, u32* __restrict__ nbrcnt,
                      u32* __restrict__ nbrlst, int n){
    int t = blockIdx.x * blockDim.x + threadIdx.x;
    int pt = t / 27;
    if(pt >= n) return;
    int d = t - pt * 27;
    if(d == 13) return;                          // self handled densely in k_pre2
    int4 c = ((const int4*)coords)[pt];
    int nx = c.x + d / 9 - 1, ny = c.y + (d / 3) % 3 - 1, nz = c.z + d % 3 - 1;
    if(((u32)nx >= 256u) | ((u32)ny >= 256u) | ((u32)nz >= 256u)) return;
    u32 b = ((u32)nx << 16) | ((u32)ny << 8) | (u32)nz;
    if(!((bm[b >> 5] >> (b & 31)) & 1u)) return;
    u32 s = hslot(b);
    u64 e;
    while((u32)((e = hash[s]) >> 32) != b) s = (s + 1) & HMASK;
    u32 slot = atomicAdd(&nbrcnt[pt], 1u);
    if(slot < 8u) nbrlst[(size_t)pt * 8 + slot] = ((u32)d << 25) | (u32)e;
}

// F_input = LN(feats @ W_pre^T). ONE resident weight array.
__launch_bounds__(256)
__global__ void k_pre1(const float* __restrict__ feats, const float* __restrict__ W_pre,
                       const float* __restrict__ lnw, const float* __restrict__ lnb,
                       float* __restrict__ F_input, int n, int nwaves){
    const int lane = threadIdx.x & 63;
    const int wave = (blockIdx.x * blockDim.x + threadIdx.x) >> 6;

    float W[64];   // W_pre[lane][j]
    {   const float4* wr = (const float4*)(W_pre + (size_t)lane * 64);
#pragma unroll
        for(int q = 0; q < 16; ++q){
            float4 v = wr[q];
            W[4*q] = v.x; W[4*q+1] = v.y; W[4*q+2] = v.z; W[4*q+3] = v.w;
        }
    }
    const float lw = lnw[lane], lb = lnb[lane];

    for(int i = wave; i < n; i += nwaves){
        const int si = __builtin_amdgcn_readfirstlane(i);
        const float4* fr = (const float4*)(feats + (size_t)si * 64);
        float a0=0.f, a1=0.f, a2=0.f, a3=0.f;
#pragma unroll
        for(int q = 0; q < 16; ++q){
            float4 f = fr[q];
            a0 = fmaf(f.x, W[4*q],   a0);
            a1 = fmaf(f.y, W[4*q+1], a1);
            a2 = fmaf(f.z, W[4*q+2], a2);
            a3 = fmaf(f.w, W[4*q+3], a3);
        }
        float acc = (a0 + a1) + (a2 + a3);
        float m = wave_sum(acc) * (1.f/64.f);
        float t = acc - m;
        float v = wave_sum(t*t) * (1.f/64.f);
        F_input[(size_t)si*64 + lane] = t * rsqrtf(v + EPSV) * lw + lb;
    }
}

// selfconv = feats @ conv_w[13]. ONE resident weight array.
__launch_bounds__(256)
__global__ void k_pre2(const float* __restrict__ feats, const float* __restrict__ conv_w,
                       float* __restrict__ selfconv, int n, int nwaves){
    const int lane = threadIdx.x & 63;
    const int wave = (blockIdx.x * blockDim.x + threadIdx.x) >> 6;

    float W13[64]; // conv_w[13][j][lane]
#pragma unroll
    for(int j = 0; j < 64; ++j) W13[j] = conv_w[(13*64 + j)*64 + lane];

    for(int i = wave; i < n; i += nwaves){
        const int si = __builtin_amdgcn_readfirstlane(i);
        const float4* fr = (const float4*)(feats + (size_t)si * 64);
        float s0=0.f, s1=0.f, s2=0.f, s3=0.f;
#pragma unroll
        for(int q = 0; q < 16; ++q){
            float4 f = fr[q];
            s0 = fmaf(f.x, W13[4*q],   s0);
            s1 = fmaf(f.y, W13[4*q+1], s1);
            s2 = fmaf(f.z, W13[4*q+2], s2);
            s3 = fmaf(f.w, W13[4*q+3], s3);
        }
        selfconv[(size_t)si*64 + lane] = (s0 + s1) + (s2 + s3);
    }
}

// Segment sums: 1 wave = 1 segment; lane-parallel hash probes; no atomics.
__launch_bounds__(256)
__global__ void k_seg(const float* __restrict__ F_input, const u64* __restrict__ hash,
                      const u64* __restrict__ bm64, const float* __restrict__ W_pos,
                      const float* __restrict__ alpha,
                      float* __restrict__ sums, float* __restrict__ counts){
    const int lane = threadIdx.x & 63;
    const int seg  = (blockIdx.x << 2) + (threadIdx.x >> 6);
    const int cx = seg >> 10, cy = (seg >> 5) & 31, cz = seg & 31;

    const int px = (cx << 3) + (lane >> 3), py = (cy << 3) + (lane & 7);
    u64 w = bm64[((size_t)px << 10) | ((u32)py << 2) | (u32)(cz >> 3)];
    u32 o8 = (u32)(w >> ((cz & 7) * 8)) & 0xffu;
    float cnt = wave_sum((float)__popc(o8));

    const float wx = W_pos[lane*3+0], wy = W_pos[lane*3+1], wz = W_pos[lane*3+2];
    const float al = alpha[lane];

    float aC = 0.f, aS = 0.f, aL = 0.f;
    while(__ballot(o8 != 0u)){
        int myz = 0, pid = -1;
        if(o8){
            int dz = __ffs(o8) - 1; o8 &= o8 - 1;
            myz = (cz << 3) + dz;
            u32 b = ((u32)px << 16) | ((u32)py << 8) | (u32)myz;
            u32 s = hslot(b); u64 e;
            while((u32)((e = hash[s]) >> 32) != b) s = (s + 1) & HMASK;   // lane-parallel
            pid = (int)(u32)e;
        }
        u64 mm = __ballot(pid >= 0);
        while(mm){
            int l = __ffsll(mm) - 1; mm &= mm - 1;
            int p  = __builtin_amdgcn_readlane(pid, l);
            int pz = __builtin_amdgcn_readlane(myz, l);
            int qx = (cx << 3) + (l >> 3), qy = (cy << 3) + (l & 7);
            float F = F_input[(size_t)p * 64 + lane];
            float pos = ((float)qx*wx + (float)qy*wy + (float)pz*wz) * al;
            aC = fmaf(F, __cosf(pos), aC);
            aS = fmaf(F, __sinf(pos), aS);
            aL = fmaf(F, pos, aL);
        }
    }
    float* sp = sums + (size_t)seg * 192;
    sp[lane] = aC; sp[64 + lane] = aS; sp[128 + lane] = aL;
    if(lane == 0) counts[seg] = cnt;
}

// Software-pipelined final (r7 verbatim — spill-free at VGPR~68).
__launch_bounds__(256)
__global__ void k_final(const float* __restrict__ feats,
                        const float* __restrict__ F_input,
                        const float* __restrict__ selfconv,
                        const float* __restrict__ W_pos, const float* __restrict__ alpha,
                        const float* __restrict__ conv_w,
                        const float* __restrict__ ln_w, const float* __restrict__ ln_b,
                        const float* __restrict__ lnl_w, const float* __restrict__ lnl_b,
                        const int* __restrict__ coords,
                        const float* __restrict__ sums, const float* __restrict__ counts,
                        const u32* __restrict__ nbrcnt, const u32* __restrict__ nbrlst,
                        float* __restrict__ out, int n, int nwaves){
    const int lane = threadIdx.x & 63;
    const int wave = (blockIdx.x * blockDim.x + threadIdx.x) >> 6;

    const float wx = W_pos[lane*3+0], wy = W_pos[lane*3+1], wz = W_pos[lane*3+2];
    const float al = alpha[lane];
    const float lnwv = ln_w[lane], lnbv = ln_b[lane];
    const float llwv = lnl_w[lane], llbv = lnl_b[lane];

    int i = wave;
    if(i >= n) return;

    int siA = __builtin_amdgcn_readfirstlane(i);
    int4 cA = ((const int4*)coords)[siA];
    int segA = ((cA.x >> 3) << 10) | ((cA.y >> 3) << 5) | (cA.z >> 3);
    const float* spA = sums + (size_t)segA * 192;
    float s0A = spA[lane], s1A = spA[64+lane], s2A = spA[128+lane];
    float cntA = counts[segA];
    float FA = F_input[(size_t)siA*64 + lane];
    float ScA = selfconv[(size_t)siA*64 + lane];
    u32 ncA = nbrcnt[siA];
    u32 e0A = nbrlst[(size_t)siA*8];

    for(; i < n; ){
        const int inext = i + nwaves;
        const bool hB = inext < n;
        int siB = 0; int4 cB = cA; float s0B=0,s1B=0,s2B=0,cntB=0,FB=0,ScB=0;
        u32 ncB = 0, e0B = 0;
        if(hB){
            siB = __builtin_amdgcn_readfirstlane(inext);
            cB = ((const int4*)coords)[siB];
            int segB = ((cB.x >> 3) << 10) | ((cB.y >> 3) << 5) | (cB.z >> 3);
            const float* spB = sums + (size_t)segB * 192;
            s0B = spB[lane]; s1B = spB[64+lane]; s2B = spB[128+lane];
            cntB = counts[segB];
            FB = F_input[(size_t)siB*64 + lane];
            ScB = selfconv[(size_t)siB*64 + lane];
            ncB = nbrcnt[siB];
            e0B = nbrlst[(size_t)siB*8];
        }

        // ---- compute A ----
        float pos = ((float)cA.x*wx + (float)cA.y*wy + (float)cA.z*wz) * al;
        float sn = __sinf(pos), cs = __cosf(pos);
        float inv = 1.f / fmaxf(cntA, 1.f);
        float newF = fmaf(s0A*inv, cs, fmaf(s1A*inv, sn, s2A*inv - FA*pos));
        float local = ScA;

        u32 cc = ncA > 8u ? 8u : ncA;
        if(cc){
            u32 e = e0A;
            u32 c2 = 0;
            for(;;){
                u32 k = e >> 25, pi = e & 0x1FFFFFFu;
                const float4* gv = (const float4*)(feats + (size_t)pi * 64);
                const float* cw = conv_w + (size_t)k * 4096;
#pragma unroll
                for(int q = 0; q < 16; ++q){
                    float4 g = gv[q];
                    local = fmaf(g.x, cw[(4*q    )*64 + lane], local);
                    local = fmaf(g.y, cw[(4*q + 1)*64 + lane], local);
                    local = fmaf(g.z, cw[(4*q + 2)*64 + lane], local);
                    local = fmaf(g.w, cw[(4*q + 3)*64 + lane], local);
                }
                if(++c2 >= cc) break;
                e = nbrlst[(size_t)siA*8 + c2];
            }
        }

        float m1 = wave_sum(newF) * (1.f/64.f);
        float t1 = newF - m1;
        float v1 = wave_sum(t1*t1) * (1.f/64.f);
        float a1 = t1 * rsqrtf(v1 + EPSV) * lnwv + lnbv;

        float m2 = wave_sum(local) * (1.f/64.f);
        float t2 = local - m2;
        float v2 = wave_sum(t2*t2) * (1.f/64.f);
        float a2 = t2 * rsqrtf(v2 + EPSV) * llwv + llbv;

        out[(size_t)siA*64 + lane] = fmaxf(a1 + a2, 0.f);

        i = inext;
        if(hB){
            siA = siB; cA = cB;
            s0A = s0B; s1A = s1B; s2A = s2B; cntA = cntB;
            FA = FB; ScA = ScB; ncA = ncB; e0A = e0B;
        }
    }
}

extern "C" void kernel_launch(void* const* d_in, const int* in_sizes, int n_in,
                              void* d_out, int out_size, void* d_ws, size_t ws_size,
                              hipStream_t stream) {
    (void)n_in; (void)out_size; (void)ws_size;
    const float* feats    = (const float*)d_in[0];
    const float* W_pre    = (const float*)d_in[1];
    const float* ln_pre_w = (const float*)d_in[2];
    const float* ln_pre_b = (const float*)d_in[3];
    const float* W_pos    = (const float*)d_in[4];
    const float* alpha    = (const float*)d_in[5];
    const float* conv_w   = (const float*)d_in[6];
    const float* ln_w     = (const float*)d_in[7];
    const float* ln_b     = (const float*)d_in[8];
    const float* lnl_w    = (const float*)d_in[9];
    const float* lnl_b    = (const float*)d_in[10];
    const int*   coords   = (const int*)d_in[11];

    const int n = in_sizes[0] / 64;

    char* ws = (char*)d_ws;
    size_t o = 0;
    u64*   hash    = (u64*)(ws + o);   o += (size_t)HSIZE * 8;          // 8,388,608
    size_t zoff    = o;
    u32*   bm      = (u32*)(ws + o);   o += 2097152;                    // 2MB bitmap
    u64*   bm64    = (u64*)bm;
    u32*   nbrcnt  = (u32*)(ws + o);   o += ((size_t)n*4 + 255) & ~(size_t)255;
    size_t zspan   = o - zoff;
    float* sums    = (float*)(ws + o); o += 25165824;                   // written by k_seg (no memset)
    float* counts  = (float*)(ws + o); o += 131072;                     // written by k_seg
    u32*   nbrlst  = (u32*)(ws + o);   o += (size_t)n * 32;             // 8 slots/pt
    float* F_input = (float*)(ws + o); o += (size_t)n * 256;
    float* selfconv= (float*)(ws + o); o += (size_t)n * 256;

    hipMemsetAsync(hash, 0xFF, (size_t)HSIZE * 8, stream);
    hipMemsetAsync(ws + zoff, 0, zspan, stream);

    k_scatter<<<(n + 255)/256, 256, 0, stream>>>(coords, hash, bm, n);
    k_nbr<<<(n*27 + 255)/256, 256, 0, stream>>>(coords, hash, bm, nbrcnt, nbrlst, n);
    k_pre1<<<2048, 256, 0, stream>>>(feats, W_pre, ln_pre_w, ln_pre_b, F_input, n, 8192);
    k_pre2<<<2048, 256, 0, stream>>>(feats, conv_w, selfconv, n, 8192);
    k_seg<<<8192, 256, 0, stream>>>(F_input, hash, bm64, W_pos, alpha, sums, counts);
    k_final<<<2048, 256, 0, stream>>>(feats, F_input, selfconv, W_pos, alpha, conv_w,
                                      ln_w, ln_b, lnl_w, lnl_b, coords,
                                      sums, counts, nbrcnt, nbrlst,
                                      (float*)d_out, n, 8192);
}

// Round 10
// 257.232 us; speedup vs baseline: 1.8894x; 1.3331x over previous
//
#include <hip/hip_runtime.h>

// ELKUNet forward on MI355X — round 10. f32 device tensors (proven r1/r2/r4/r5).
// r9 -> r10: concurrency. Dependency graph: scatter->{nbr}; pre1->{seg};
// {scatter,pre1,pre2} mutually independent; {nbr,seg} mutually independent.
// => two role-merged launches (block-range dispatch):
//    mega1 = scatter || pre1 || pre2      mega2 = seg || nbr
// Latency-bound roles fill each other's stalls instead of running serially.
// k_final: #pragma unroll 4 on the conv loop to cut in-flight VGPR (r9: 88,
// 4 waves/SIMD; target <=64 -> 8 waves/SIMD). Hash 8MB->4MB (L2-resident).

typedef unsigned int u32;
typedef unsigned long long u64;

#define EPSV 1e-6f
#define HBITS 19
#define HSIZE (1u << HBITS)
#define HMASK (HSIZE - 1u)

template<int C,int R> __device__ __forceinline__ float dpp_add(float x){
    int y = __builtin_amdgcn_update_dpp(0, __float_as_int(x), C, R, 0xf, true);
    return x + __int_as_float(y);
}
// full 64-lane sum broadcast to all lanes; pure VALU + 1 readlane.
__device__ __forceinline__ float wave_sum(float x){
    x = dpp_add<0xB1,0xF>(x);   // xor 1
    x = dpp_add<0x4E,0xF>(x);   // xor 2
    x = dpp_add<0x141,0xF>(x);  // xor 4
    x = dpp_add<0x140,0xF>(x);  // xor 8
    x = dpp_add<0x142,0xA>(x);  // row_bcast:15
    x = dpp_add<0x143,0xC>(x);  // row_bcast:31
    return __int_as_float(__builtin_amdgcn_readlane(__float_as_int(x), 63));
}

__device__ __forceinline__ u32 hslot(u32 b){ return (b * 0x9E3779B1u) >> (32 - HBITS); }

// ---- mega1: scatter || pre1 || pre2 -------------------------------------
__launch_bounds__(256)
__global__ void mega1(const float* __restrict__ feats, const float* __restrict__ W_pre,
                      const float* __restrict__ lnw, const float* __restrict__ lnb,
                      const float* __restrict__ conv_w,
                      const int* __restrict__ coords,
                      u64* __restrict__ hash, u32* __restrict__ bm,
                      float* __restrict__ F_input, float* __restrict__ selfconv,
                      int n, int sBlocks, int pBlocks){
    const int b = blockIdx.x;
    const int lane = threadIdx.x & 63;

    if(b < sBlocks){                                   // ---- scatter ----
        int i = b * 256 + threadIdx.x;
        if(i < n){
            int4 c = ((const int4*)coords)[i];
            u32 bb = ((u32)c.x << 16) | ((u32)c.y << 8) | (u32)c.z;
            atomicOr(&bm[bb >> 5], 1u << (bb & 31));
            u64 entry = ((u64)bb << 32) | (u32)i;
            u32 s = hslot(bb);
            while(atomicCAS(&hash[s], ~0ull, entry) != ~0ull) s = (s + 1) & HMASK;
        }
        return;
    }
    const int nwaves = pBlocks * 4;
    if(b < sBlocks + pBlocks){                         // ---- pre1 ----
        const int wave = (b - sBlocks) * 4 + (threadIdx.x >> 6);
        float W[64];   // W_pre[lane][j]
        {   const float4* wr = (const float4*)(W_pre + (size_t)lane * 64);
#pragma unroll
            for(int q = 0; q < 16; ++q){
                float4 v = wr[q];
                W[4*q] = v.x; W[4*q+1] = v.y; W[4*q+2] = v.z; W[4*q+3] = v.w;
            }
        }
        const float lw = lnw[lane], lb = lnb[lane];
        for(int i = wave; i < n; i += nwaves){
            const int si = __builtin_amdgcn_readfirstlane(i);
            const float4* fr = (const float4*)(feats + (size_t)si * 64);
            float a0=0.f, a1=0.f, a2=0.f, a3=0.f;
#pragma unroll
            for(int q = 0; q < 16; ++q){
                float4 f = fr[q];
                a0 = fmaf(f.x, W[4*q],   a0);
                a1 = fmaf(f.y, W[4*q+1], a1);
                a2 = fmaf(f.z, W[4*q+2], a2);
                a3 = fmaf(f.w, W[4*q+3], a3);
            }
            float acc = (a0 + a1) + (a2 + a3);
            float m = wave_sum(acc) * (1.f/64.f);
            float t = acc - m;
            float v = wave_sum(t*t) * (1.f/64.f);
            F_input[(size_t)si*64 + lane] = t * rsqrtf(v + EPSV) * lw + lb;
        }
        return;
    }
    {                                                  // ---- pre2 ----
        const int wave = (b - sBlocks - pBlocks) * 4 + (threadIdx.x >> 6);
        float W13[64]; // conv_w[13][j][lane]
#pragma unroll
        for(int j = 0; j < 64; ++j) W13[j] = conv_w[(13*64 + j)*64 + lane];
        for(int i = wave; i < n; i += nwaves){
            const int si = __builtin_amdgcn_readfirstlane(i);
            const float4* fr = (const float4*)(feats + (size_t)si * 64);
            float s0=0.f, s1=0.f, s2=0.f, s3=0.f;
#pragma unroll
            for(int q = 0; q < 16; ++q){
                float4 f = fr[q];
                s0 = fmaf(f.x, W13[4*q],   s0);
                s1 = fmaf(f.y, W13[4*q+1], s1);
                s2 = fmaf(f.z, W13[4*q+2], s2);
                s3 = fmaf(f.w, W13[4*q+3], s3);
            }
            selfconv[(size_t)si*64 + lane] = (s0 + s1) + (s2 + s3);
        }
    }
}

// ---- mega2: seg || nbr ---------------------------------------------------
__launch_bounds__(256)
__global__ void mega2(const float* __restrict__ F_input,
                      const float* __restrict__ W_pos, const float* __restrict__ alpha,
                      const int* __restrict__ coords,
                      const u64* __restrict__ hash, const u32* __restrict__ bm,
                      float* __restrict__ sums, float* __restrict__ counts,
                      u32* __restrict__ nbrcnt, u32* __restrict__ nbrlst,
                      int n, int segBlocks){
    const int b = blockIdx.x;
    const int lane = threadIdx.x & 63;

    if(b < segBlocks){                                 // ---- seg ----
        const u64* bm64 = (const u64*)bm;
        const int seg  = (b << 2) + (threadIdx.x >> 6);
        const int cx = seg >> 10, cy = (seg >> 5) & 31, cz = seg & 31;
        const int px = (cx << 3) + (lane >> 3), py = (cy << 3) + (lane & 7);
        u64 w = bm64[((size_t)px << 10) | ((u32)py << 2) | (u32)(cz >> 3)];
        u32 o8 = (u32)(w >> ((cz & 7) * 8)) & 0xffu;
        float cnt = wave_sum((float)__popc(o8));

        const float wx = W_pos[lane*3+0], wy = W_pos[lane*3+1], wz = W_pos[lane*3+2];
        const float al = alpha[lane];
        float aC = 0.f, aS = 0.f, aL = 0.f;
        while(__ballot(o8 != 0u)){
            int myz = 0, pid = -1;
            if(o8){
                int dz = __ffs(o8) - 1; o8 &= o8 - 1;
                myz = (cz << 3) + dz;
                u32 bb = ((u32)px << 16) | ((u32)py << 8) | (u32)myz;
                u32 s = hslot(bb); u64 e;
                while((u32)((e = hash[s]) >> 32) != bb) s = (s + 1) & HMASK;
                pid = (int)(u32)e;
            }
            u64 mm = __ballot(pid >= 0);
            while(mm){
                int l = __ffsll(mm) - 1; mm &= mm - 1;
                int p  = __builtin_amdgcn_readlane(pid, l);
                int pz = __builtin_amdgcn_readlane(myz, l);
                int qx = (cx << 3) + (l >> 3), qy = (cy << 3) + (l & 7);
                float F = F_input[(size_t)p * 64 + lane];
                float pos = ((float)qx*wx + (float)qy*wy + (float)pz*wz) * al;
                aC = fmaf(F, __cosf(pos), aC);
                aS = fmaf(F, __sinf(pos), aS);
                aL = fmaf(F, pos, aL);
            }
        }
        float* sp = sums + (size_t)seg * 192;
        sp[lane] = aC; sp[64 + lane] = aS; sp[128 + lane] = aL;
        if(lane == 0) counts[seg] = cnt;
        return;
    }
    {                                                  // ---- nbr ----
        int t = (b - segBlocks) * 256 + threadIdx.x;
        int pt = t / 27;
        if(pt >= n) return;
        int d = t - pt * 27;
        if(d == 13) return;
        int4 c = ((const int4*)coords)[pt];
        int nx = c.x + d / 9 - 1, ny = c.y + (d / 3) % 3 - 1, nz = c.z + d % 3 - 1;
        if(((u32)nx >= 256u) | ((u32)ny >= 256u) | ((u32)nz >= 256u)) return;
        u32 bb = ((u32)nx << 16) | ((u32)ny << 8) | (u32)nz;
        if(!((bm[bb >> 5] >> (bb & 31)) & 1u)) return;
        u32 s = hslot(bb);
        u64 e;
        while((u32)((e = hash[s]) >> 32) != bb) s = (s + 1) & HMASK;
        u32 slot = atomicAdd(&nbrcnt[pt], 1u);
        if(slot < 8u) nbrlst[(size_t)pt * 8 + slot] = ((u32)d << 25) | (u32)e;
    }
}

// Software-pipelined final (r7/r9 form); conv loop unroll-capped to 4 to cut
// in-flight VGPR (r9: 88 -> target <=64 for 8 waves/SIMD).
__launch_bounds__(256)
__global__ void k_final(const float* __restrict__ feats,
                        const float* __restrict__ F_input,
                        const float* __restrict__ selfconv,
                        const float* __restrict__ W_pos, const float* __restrict__ alpha,
                        const float* __restrict__ conv_w,
                        const float* __restrict__ ln_w, const float* __restrict__ ln_b,
                        const float* __restrict__ lnl_w, const float* __restrict__ lnl_b,
                        const int* __restrict__ coords,
                        const float* __restrict__ sums, const float* __restrict__ counts,
                        const u32* __restrict__ nbrcnt, const u32* __restrict__ nbrlst,
                        float* __restrict__ out, int n, int nwaves){
    const int lane = threadIdx.x & 63;
    const int wave = (blockIdx.x * blockDim.x + threadIdx.x) >> 6;

    const float wx = W_pos[lane*3+0], wy = W_pos[lane*3+1], wz = W_pos[lane*3+2];
    const float al = alpha[lane];
    const float lnwv = ln_w[lane], lnbv = ln_b[lane];
    const float llwv = lnl_w[lane], llbv = lnl_b[lane];

    int i = wave;
    if(i >= n) return;

    int siA = __builtin_amdgcn_readfirstlane(i);
    int4 cA = ((const int4*)coords)[siA];
    int segA = ((cA.x >> 3) << 10) | ((cA.y >> 3) << 5) | (cA.z >> 3);
    const float* spA = sums + (size_t)segA * 192;
    float s0A = spA[lane], s1A = spA[64+lane], s2A = spA[128+lane];
    float cntA = counts[segA];
    float FA = F_input[(size_t)siA*64 + lane];
    float ScA = selfconv[(size_t)siA*64 + lane];
    u32 ncA = nbrcnt[siA];
    u32 e0A = nbrlst[(size_t)siA*8];

    for(; i < n; ){
        const int inext = i + nwaves;
        const bool hB = inext < n;
        int siB = 0; int4 cB = cA; float s0B=0,s1B=0,s2B=0,cntB=0,FB=0,ScB=0;
        u32 ncB = 0, e0B = 0;
        if(hB){
            siB = __builtin_amdgcn_readfirstlane(inext);
            cB = ((const int4*)coords)[siB];
            int segB = ((cB.x >> 3) << 10) | ((cB.y >> 3) << 5) | (cB.z >> 3);
            const float* spB = sums + (size_t)segB * 192;
            s0B = spB[lane]; s1B = spB[64+lane]; s2B = spB[128+lane];
            cntB = counts[segB];
            FB = F_input[(size_t)siB*64 + lane];
            ScB = selfconv[(size_t)siB*64 + lane];
            ncB = nbrcnt[siB];
            e0B = nbrlst[(size_t)siB*8];
        }

        // ---- compute A ----
        float pos = ((float)cA.x*wx + (float)cA.y*wy + (float)cA.z*wz) * al;
        float sn = __sinf(pos), cs = __cosf(pos);
        float inv = 1.f / fmaxf(cntA, 1.f);
        float newF = fmaf(s0A*inv, cs, fmaf(s1A*inv, sn, s2A*inv - FA*pos));
        float local = ScA;

        u32 cc = ncA > 8u ? 8u : ncA;
        if(cc){
            u32 e = e0A;
            u32 c2 = 0;
            for(;;){
                u32 k = e >> 25, pi = e & 0x1FFFFFFu;
                const float4* gv = (const float4*)(feats + (size_t)pi * 64);
                const float* cw = conv_w + (size_t)k * 4096;
#pragma unroll 4
                for(int q = 0; q < 16; ++q){
                    float4 g = gv[q];
                    local = fmaf(g.x, cw[(4*q    )*64 + lane], local);
                    local = fmaf(g.y, cw[(4*q + 1)*64 + lane], local);
                    local = fmaf(g.z, cw[(4*q + 2)*64 + lane], local);
                    local = fmaf(g.w, cw[(4*q + 3)*64 + lane], local);
                }
                if(++c2 >= cc) break;
                e = nbrlst[(size_t)siA*8 + c2];
            }
        }

        float m1 = wave_sum(newF) * (1.f/64.f);
        float t1 = newF - m1;
        float v1 = wave_sum(t1*t1) * (1.f/64.f);
        float a1 = t1 * rsqrtf(v1 + EPSV) * lnwv + lnbv;

        float m2 = wave_sum(local) * (1.f/64.f);
        float t2 = local - m2;
        float v2 = wave_sum(t2*t2) * (1.f/64.f);
        float a2 = t2 * rsqrtf(v2 + EPSV) * llwv + llbv;

        out[(size_t)siA*64 + lane] = fmaxf(a1 + a2, 0.f);

        i = inext;
        if(hB){
            siA = siB; cA = cB;
            s0A = s0B; s1A = s1B; s2A = s2B; cntA = cntB;
            FA = FB; ScA = ScB; ncA = ncB; e0A = e0B;
        }
    }
}

extern "C" void kernel_launch(void* const* d_in, const int* in_sizes, int n_in,
                              void* d_out, int out_size, void* d_ws, size_t ws_size,
                              hipStream_t stream) {
    (void)n_in; (void)out_size; (void)ws_size;
    const float* feats    = (const float*)d_in[0];
    const float* W_pre    = (const float*)d_in[1];
    const float* ln_pre_w = (const float*)d_in[2];
    const float* ln_pre_b = (const float*)d_in[3];
    const float* W_pos    = (const float*)d_in[4];
    const float* alpha    = (const float*)d_in[5];
    const float* conv_w   = (const float*)d_in[6];
    const float* ln_w     = (const float*)d_in[7];
    const float* ln_b     = (const float*)d_in[8];
    const float* lnl_w    = (const float*)d_in[9];
    const float* lnl_b    = (const float*)d_in[10];
    const int*   coords   = (const int*)d_in[11];

    const int n = in_sizes[0] / 64;

    char* ws = (char*)d_ws;
    size_t o = 0;
    u64*   hash    = (u64*)(ws + o);   o += (size_t)HSIZE * 8;          // 4,194,304
    size_t zoff    = o;
    u32*   bm      = (u32*)(ws + o);   o += 2097152;                    // 2MB bitmap
    u32*   nbrcnt  = (u32*)(ws + o);   o += ((size_t)n*4 + 255) & ~(size_t)255;
    size_t zspan   = o - zoff;
    float* sums    = (float*)(ws + o); o += 25165824;                   // written by seg (no memset)
    float* counts  = (float*)(ws + o); o += 131072;                     // written by seg
    u32*   nbrlst  = (u32*)(ws + o);   o += (size_t)n * 32;             // 8 slots/pt
    float* F_input = (float*)(ws + o); o += (size_t)n * 256;
    float* selfconv= (float*)(ws + o); o += (size_t)n * 256;

    hipMemsetAsync(hash, 0xFF, (size_t)HSIZE * 8, stream);
    hipMemsetAsync(ws + zoff, 0, zspan, stream);

    const int sBlocks = (n + 255) / 256;              // 782
    const int pBlocks = 2048;
    mega1<<<sBlocks + 2*pBlocks, 256, 0, stream>>>(feats, W_pre, ln_pre_w, ln_pre_b,
                                                   conv_w, coords, hash, bm,
                                                   F_input, selfconv, n, sBlocks, pBlocks);

    const int segBlocks = 8192;                       // 32768 segments / 4
    const int nbrBlocks = (n*27 + 255) / 256;         // 21094
    mega2<<<segBlocks + nbrBlocks, 256, 0, stream>>>(F_input, W_pos, alpha, coords,
                                                     hash, bm, sums, counts,
                                                     nbrcnt, nbrlst, n, segBlocks);

    k_final<<<2048, 256, 0, stream>>>(feats, F_input, selfconv, W_pos, alpha, conv_w,
                                      ln_w, ln_b, lnl_w, lnl_b, coords,
                                      sums, counts, nbrcnt, nbrlst,
                                      (float*)d_out, n, 8192);
}